// Round 4
// baseline (907.388 us; speedup 1.0000x reference)
//
#include <hip/hip_runtime.h>
#include <hip/hip_bf16.h>
#include <cstdint>
#include <cstddef>

#define BB 2
#define LL 1024
#define DM 768
#define DI 1536
#define NS 16
#define DTR 48
#define TEMB_ 1024
#define WSPAD 16

typedef unsigned short ushort_;
using bf16x8 = __attribute__((ext_vector_type(8))) short;
using f32x4  = __attribute__((ext_vector_type(4))) float;

static __device__ __forceinline__ float sigmoidf_(float x){ return 1.f/(1.f+__expf(-x)); }
static __device__ __forceinline__ float siluf_(float x){ return x*sigmoidf_(x); }
static __device__ __forceinline__ float softplusf_(float x){ return (x>15.f)? x : log1pf(__expf(x)); }

static __device__ __forceinline__ void split2(float v, ushort_& h, ushort_& l){
  __hip_bfloat16 bh = __float2bfloat16(v);
  float hf = __bfloat162float(bh);
  __hip_bfloat16 bl = __float2bfloat16(v - hf);
  h = *(ushort_*)&bh; l = *(ushort_*)&bl;
}

// ---------- cross-lane helpers: pure-VALU DPP, 16-lane groups ----------
// quad_perm 0xB1 = xor1, 0x4E = xor2; row_half_mirror 0x141 = xor7; row_mirror 0x140 = xor15.
#define DPPX(CTRL, x) __int_as_float(__builtin_amdgcn_update_dpp(0, __float_as_int(x), (CTRL), 0xF, 0xF, true))

static __device__ __forceinline__ float sum16(float x){
  x += DPPX(0xB1, x);
  x += DPPX(0x4E, x);
  x += DPPX(0x141, x);
  x += DPPX(0x140, x);
  return x;
}

// ---------- K0: emb path ----------
__global__ __launch_bounds__(128) void emb_kernel(const float* __restrict__ emb,
                                                  const float* __restrict__ We,
                                                  const float* __restrict__ be,
                                                  float* __restrict__ eo){
  __shared__ float se[TEMB_];
  const int b = blockIdx.x / 12;
  const int jb = (blockIdx.x % 12) * 128;
  for (int i = threadIdx.x; i < TEMB_; i += 128) se[i] = siluf_(emb[b*TEMB_ + i]);
  __syncthreads();
  const int j = jb + threadIdx.x;
  const float* wr = We + (size_t)j * TEMB_;
  float acc = 0.f;
  #pragma unroll 4
  for (int k = 0; k < TEMB_; k += 4){
    acc = fmaf(se[k+0], wr[k+0], acc);
    acc = fmaf(se[k+1], wr[k+1], acc);
    acc = fmaf(se[k+2], wr[k+2], acc);
    acc = fmaf(se[k+3], wr[k+3], acc);
  }
  eo[b*(2*DM) + j] = acc + be[j];
}

// ---------- K1: RMSNorm -> split bf16 hi/lo ----------
__global__ __launch_bounds__(256) void rmsnorm_split_kernel(const float* __restrict__ x,
                                                            const float* __restrict__ w,
                                                            ushort_* __restrict__ xh,
                                                            ushort_* __restrict__ xl){
  const int row = blockIdx.x;
  const int tid = threadIdx.x;
  const float* xp = x + (size_t)row * DM;
  float vals[3];
  float p = 0.f;
  #pragma unroll
  for (int i = 0; i < 3; i++){ float v = xp[tid + i*256]; vals[i] = v; p += v*v; }
  #pragma unroll
  for (int off = 32; off; off >>= 1) p += __shfl_xor(p, off);
  __shared__ float wsum[4];
  if ((tid & 63) == 0) wsum[tid >> 6] = p;
  __syncthreads();
  float total = wsum[0] + wsum[1] + wsum[2] + wsum[3];
  float rs = rsqrtf(total * (1.f/768.f) + 1e-5f);
  #pragma unroll
  for (int i = 0; i < 3; i++){
    int j = tid + i*256;
    float v = vals[i]*rs*w[j];
    ushort_ h, l; split2(v, h, l);
    xh[(size_t)row*DM + j] = h;
    xl[(size_t)row*DM + j] = l;
  }
}

// ---------- generic fp32 -> bf16 hi/lo split ----------
__global__ __launch_bounds__(256) void split_kernel(const float* __restrict__ in,
                                                    ushort_* __restrict__ h,
                                                    ushort_* __restrict__ l, int n4){
  const int i = blockIdx.x*256 + threadIdx.x;
  if (i >= n4) return;
  float4 v = ((const float4*)in)[i];
  ushort4 hh, ll;
  split2(v.x, hh.x, ll.x); split2(v.y, hh.y, ll.y);
  split2(v.z, hh.z, ll.z); split2(v.w, hh.w, ll.w);
  ((ushort4*)h)[i] = hh; ((ushort4*)l)[i] = ll;
}

// ---------- K2: depthwise causal conv (k=4) + bias + SiLU ----------
__global__ __launch_bounds__(256) void conv_silu_kernel(const float* __restrict__ xr,
                                                        const float* __restrict__ cw,
                                                        const float* __restrict__ cb,
                                                        float* __restrict__ uc){
  const int d  = blockIdx.x*256 + threadIdx.x;
  const int bt = blockIdx.y;
  const int t  = bt & (LL-1);
  const float w0 = cw[d*4+0], w1 = cw[d*4+1], w2 = cw[d*4+2], w3 = cw[d*4+3];
  const float* up = xr + (size_t)bt*(2*DI) + d;
  float s = cb[d];
  if (t >= 3) s = fmaf(up[-3*2*DI], w0, s);
  if (t >= 2) s = fmaf(up[-2*2*DI], w1, s);
  if (t >= 1) s = fmaf(up[-1*2*DI], w2, s);
  s = fmaf(up[0], w3, s);
  uc[(size_t)bt*DI + d] = siluf_(s);
}

// ---------- fp32 tiled GEMM (kept for Wx / Wdt):  C = A * B^T ----------
template<int EPI>
__global__ __launch_bounds__(256) void gemm_nt(const float* __restrict__ A, int lda,
                                               const float* __restrict__ B, int ldb,
                                               float* __restrict__ C, int ldc,
                                               int N, int K,
                                               const float* __restrict__ bias){
  __shared__ float As[16][68];
  __shared__ float Bs[16][68];
  const int tid = threadIdx.x;
  const int m0 = blockIdx.y * 64;
  const int n0 = blockIdx.x * 64;
  const int lr = tid >> 2;
  const int lk = (tid & 3) << 2;
  const int tx = tid & 15;
  const int ty = tid >> 4;
  float acc[4][4] = {};
  for (int k0 = 0; k0 < K; k0 += 16){
    float4 ga = *(const float4*)(A + (size_t)(m0 + lr)*lda + k0 + lk);
    float4 gb;
    if (n0 + lr < N) gb = *(const float4*)(B + (size_t)(n0 + lr)*ldb + k0 + lk);
    else             gb = make_float4(0.f,0.f,0.f,0.f);
    __syncthreads();
    As[lk+0][lr] = ga.x; As[lk+1][lr] = ga.y; As[lk+2][lr] = ga.z; As[lk+3][lr] = ga.w;
    Bs[lk+0][lr] = gb.x; Bs[lk+1][lr] = gb.y; Bs[lk+2][lr] = gb.z; Bs[lk+3][lr] = gb.w;
    __syncthreads();
    #pragma unroll
    for (int k = 0; k < 16; k++){
      float4 av = *(const float4*)&As[k][ty*4];
      float4 bv = *(const float4*)&Bs[k][tx*4];
      float a4[4] = {av.x, av.y, av.z, av.w};
      float b4[4] = {bv.x, bv.y, bv.z, bv.w};
      #pragma unroll
      for (int i = 0; i < 4; i++)
        #pragma unroll
        for (int j = 0; j < 4; j++)
          acc[i][j] = fmaf(a4[i], b4[j], acc[i][j]);
    }
  }
  #pragma unroll
  for (int i = 0; i < 4; i++){
    const int row = m0 + ty*4 + i;
    #pragma unroll
    for (int j = 0; j < 4; j++){
      const int col = n0 + tx*4 + j;
      if (col < N){
        float r = acc[i][j];
        if constexpr (EPI == 1) r = softplusf_(r + bias[col]);
        C[(size_t)row*ldc + col] = r;
      }
    }
  }
}

// ---------- split-bf16 MFMA GEMM: C[M,N] = A[M,K] * B[N,K]^T ----------
// A,B pre-split into bf16 hi/lo. 128x128 tile, BK=32, 4 waves (2x2 of 64x64).
// D = Ah*Bh + Ah*Bl + Al*Bh  (AlBl dropped, ~2^-16 rel).
// mfma_f32_16x16x32_bf16: A-frag lane l: A[l&15][(l>>4)*8+j]; B-frag: B[(l>>4)*8+j][l&15];
// D lane l reg r: D[(l>>4)*4+r][l&15]   [m89/m91-verified mapping]
template<int EPI>
__global__ __launch_bounds__(256) void gemm_mfma(const ushort_* __restrict__ Ah, const ushort_* __restrict__ Al,
                                                 const ushort_* __restrict__ Bh, const ushort_* __restrict__ Bl,
                                                 float* __restrict__ C, int ldc, int K,
                                                 const float* __restrict__ bias,
                                                 const float* __restrict__ resid){
  constexpr int LDT = 40;                 // padded row (bf16): 80 B, 16B-aligned
  __shared__ ushort_ sA[2][128*LDT];
  __shared__ ushort_ sB[2][128*LDT];
  const int tid = threadIdx.x;
  const int m0 = blockIdx.y*128, n0 = blockIdx.x*128;
  const int w = tid>>6, lane = tid&63;
  const int wm = (w>>1)*64, wn = (w&1)*64;
  const int lr = lane&15, lk = lane>>4;
  const int sRow = tid>>1, sCol = (tid&1)*16;
  const size_t gA = (size_t)(m0+sRow)*K + sCol;
  const size_t gB = (size_t)(n0+sRow)*K + sCol;
  f32x4 acc[4][4] = {};
  for (int k0 = 0; k0 < K; k0 += 32){
    uint4 ah0 = *(const uint4*)(Ah + gA + k0);
    uint4 ah1 = *(const uint4*)(Ah + gA + k0 + 8);
    uint4 al0 = *(const uint4*)(Al + gA + k0);
    uint4 al1 = *(const uint4*)(Al + gA + k0 + 8);
    uint4 bh0 = *(const uint4*)(Bh + gB + k0);
    uint4 bh1 = *(const uint4*)(Bh + gB + k0 + 8);
    uint4 bl0 = *(const uint4*)(Bl + gB + k0);
    uint4 bl1 = *(const uint4*)(Bl + gB + k0 + 8);
    __syncthreads();
    *(uint4*)(&sA[0][sRow*LDT + sCol])     = ah0;
    *(uint4*)(&sA[0][sRow*LDT + sCol + 8]) = ah1;
    *(uint4*)(&sA[1][sRow*LDT + sCol])     = al0;
    *(uint4*)(&sA[1][sRow*LDT + sCol + 8]) = al1;
    *(uint4*)(&sB[0][sRow*LDT + sCol])     = bh0;
    *(uint4*)(&sB[0][sRow*LDT + sCol + 8]) = bh1;
    *(uint4*)(&sB[1][sRow*LDT + sCol])     = bl0;
    *(uint4*)(&sB[1][sRow*LDT + sCol + 8]) = bl1;
    __syncthreads();
    bf16x8 fa[2][4], fb[2][4];
    #pragma unroll
    for (int mt = 0; mt < 4; mt++){
      fa[0][mt] = *(const bf16x8*)(&sA[0][(wm+mt*16+lr)*LDT + lk*8]);
      fa[1][mt] = *(const bf16x8*)(&sA[1][(wm+mt*16+lr)*LDT + lk*8]);
      fb[0][mt] = *(const bf16x8*)(&sB[0][(wn+mt*16+lr)*LDT + lk*8]);
      fb[1][mt] = *(const bf16x8*)(&sB[1][(wn+mt*16+lr)*LDT + lk*8]);
    }
    #pragma unroll
    for (int mt = 0; mt < 4; mt++)
      #pragma unroll
      for (int nt = 0; nt < 4; nt++){
        acc[mt][nt] = __builtin_amdgcn_mfma_f32_16x16x32_bf16(fa[0][mt], fb[0][nt], acc[mt][nt], 0,0,0);
        acc[mt][nt] = __builtin_amdgcn_mfma_f32_16x16x32_bf16(fa[0][mt], fb[1][nt], acc[mt][nt], 0,0,0);
        acc[mt][nt] = __builtin_amdgcn_mfma_f32_16x16x32_bf16(fa[1][mt], fb[0][nt], acc[mt][nt], 0,0,0);
      }
  }
  #pragma unroll
  for (int mt = 0; mt < 4; mt++){
    #pragma unroll
    for (int nt = 0; nt < 4; nt++){
      const int col = n0 + wn + nt*16 + lr;
      #pragma unroll
      for (int r = 0; r < 4; r++){
        const int row = m0 + wm + mt*16 + lk*4 + r;
        float v = acc[mt][nt][r];
        if constexpr (EPI == 2) v += bias[col] + resid[(size_t)row*ldc + col];
        C[(size_t)row*ldc + col] = v;
      }
    }
  }
}

// ---------- K3b: Bm row-stats ----------
__global__ __launch_bounds__(256) void bstat_kernel(const float* __restrict__ x_dbl,
                                                    float2* __restrict__ bs){
  const int row = blockIdx.x*256 + threadIdx.x;
  const float* p = x_dbl + (size_t)row*80 + 48;
  float4 a = *(const float4*)(p);
  float4 b4 = *(const float4*)(p+4);
  float4 c4 = *(const float4*)(p+8);
  float4 d4 = *(const float4*)(p+12);
  float sm = a.x+a.y+a.z+a.w + b4.x+b4.y+b4.z+b4.w + c4.x+c4.y+c4.z+c4.w + d4.x+d4.y+d4.z+d4.w;
  float sq = a.x*a.x+a.y*a.y+a.z*a.z+a.w*a.w + b4.x*b4.x+b4.y*b4.y+b4.z*b4.z+b4.w*b4.w
           + c4.x*c4.x+c4.y*c4.y+c4.z*c4.z+c4.w*c4.w + d4.x*d4.x+d4.y*d4.y+d4.z*d4.z+d4.w*d4.w;
  float mB = sm * 0.0625f;
  float vB = fmaf(sq, 0.0625f, -(mB*mB));
  bs[row] = make_float2(mB, vB);
}

// ---------- K5: sequential scan, 2-way chain-interleaved ----------
// wave = 4 lane-groups x 2 chain-sets (d and d+4); Bm/Cm/bstat shared per t.
__global__ __launch_bounds__(64,1) void scan_kernel(const float* __restrict__ delta,
                                                    const float* __restrict__ uc,
                                                    const float* __restrict__ x_dbl,
                                                    const float2* __restrict__ bstat,
                                                    const float* __restrict__ A_log,
                                                    const float* __restrict__ Wq,
                                                    const float* __restrict__ Wk,
                                                    const float* __restrict__ Wv,
                                                    const float* __restrict__ g_s, const float* __restrict__ b_s,
                                                    const float* __restrict__ g_c, const float* __restrict__ b_c,
                                                    float* __restrict__ y){
  const int lane  = threadIdx.x & 15;
  const int chain = threadIdx.x >> 4;       // 0..3
  const int d = blockIdx.x * 8 + chain;     // X-chain; Y-chain = d+4. grid.x = 192
  const int b = blockIdx.y;

  constexpr int gseq[16] = {0,1,3,2,5,4,6,7,8,9,11,10,13,12,14,15};
  float wq[16], wk[16], wv[16];
  #pragma unroll
  for (int i = 0; i < 16; i++){
    const int c = lane ^ gseq[i];
    wq[i] = Wq[lane*16 + c];
    wk[i] = Wk[lane*16 + c];
    wv[i] = Wv[lane*16 + c];
  }
  const float adnX = -__expf(A_log[d*16 + lane]);
  const float adnY = -__expf(A_log[d*16 + 64 + lane]);
  const float gs = g_s[lane], bs0 = b_s[lane];
  const float gc = g_c[lane], bc0 = b_c[lane];

  const float* pd0 = delta + (size_t)b*LL*DI + d;
  const float* pd1 = pd0 + DI;
  const float* pd2 = pd0 + 2*DI;
  const float* pd3 = pd0 + 3*DI;
  const float* pu0 = uc + (size_t)b*LL*DI + d;
  const float* pu1 = pu0 + DI;
  const float* pu2 = pu0 + 2*DI;
  const float* pu3 = pu0 + 3*DI;
  const float* px0 = x_dbl + (size_t)b*LL*80 + 48 + lane;
  const float* px1 = px0 + 80;
  const float* px2 = px0 + 160;
  const float* px3 = px0 + 240;
  const float2* ps = bstat + (size_t)b*LL;
  float* py = y + (size_t)b*LL*DI + d;

  float sX = 0.f, sY = 0.f;

  #define DECLH(P) float P##dx0,P##dx1,P##dx2,P##dx3, P##ux0,P##ux1,P##ux2,P##ux3, \
                         P##dy0,P##dy1,P##dy2,P##dy3, P##uy0,P##uy1,P##uy2,P##uy3, \
                         P##B0,P##B1,P##B2,P##B3, P##C0,P##C1,P##C2,P##C3, \
                         P##m0,P##m1,P##m2,P##m3, P##v0,P##v1,P##v2,P##v3;
  #define LOADH(P) { \
    P##dx0=pd0[0]; P##dy0=pd0[4]; P##dx1=pd1[0]; P##dy1=pd1[4]; \
    P##dx2=pd2[0]; P##dy2=pd2[4]; P##dx3=pd3[0]; P##dy3=pd3[4]; \
    P##ux0=pu0[0]; P##uy0=pu0[4]; P##ux1=pu1[0]; P##uy1=pu1[4]; \
    P##ux2=pu2[0]; P##uy2=pu2[4]; P##ux3=pu3[0]; P##uy3=pu3[4]; \
    P##B0=px0[0]; P##B1=px1[0]; P##B2=px2[0]; P##B3=px3[0]; \
    P##C0=px0[16]; P##C1=px1[16]; P##C2=px2[16]; P##C3=px3[16]; \
    float2 t0_=ps[0], t1_=ps[1], t2_=ps[2], t3_=ps[3]; \
    P##m0=t0_.x; P##v0=t0_.y; P##m1=t1_.x; P##v1=t1_.y; \
    P##m2=t2_.x; P##v2=t2_.y; P##m3=t3_.x; P##v3=t3_.y; \
    pd0+=4*DI; pd1+=4*DI; pd2+=4*DI; pd3+=4*DI; \
    pu0+=4*DI; pu1+=4*DI; pu2+=4*DI; pu3+=4*DI; \
    px0+=320; px1+=320; px2+=320; px3+=320; ps+=4; }

  #define MV(i, CTRL) { vs = DPPX(CTRL, vs); vc = DPPX(CTRL, vc); \
    qq = fmaf(vs, wq[i], qq); kk = fmaf(vc, wk[i], kk); vv = fmaf(vc, wv[i], vv); }

  #define STEP1(SS, ADN, dv, uv, Bv, Cv, mB, vB, POFF) { \
    const float alpha = (dv)*(uv); \
    const float dA = __expf((dv) * (ADN)); \
    const float st = dA * (SS); \
    const float ssum = sum16(st); \
    const float ssq  = sum16(st*st); \
    const float m_s = ssum * 0.0625f; \
    const float v_s = fmaf(ssq, 0.0625f, -(m_s*m_s)); \
    const float k1 = rsqrtf(v_s + 1e-5f) * gs; \
    float vs = fmaf(st, k1, fmaf(-m_s, k1, bs0)); \
    const float rc = alpha * rsqrtf(fmaf(alpha*alpha, (vB), 1e-5f)); \
    const float k2 = rc * gc; \
    float vc = fmaf((Bv), k2, fmaf(-(mB), k2, bc0)); \
    float qq = vs*wq[0], kk = vc*wk[0], vv = vc*wv[0]; \
    MV(1,0xB1)  MV(2,0x4E)  MV(3,0xB1)  MV(4,0x141) \
    MV(5,0xB1)  MV(6,0x4E)  MV(7,0xB1)  MV(8,0x140) \
    MV(9,0xB1)  MV(10,0x4E) MV(11,0xB1) MV(12,0x141) \
    MV(13,0xB1) MV(14,0x4E) MV(15,0xB1) \
    const float wgt = sum16(qq*kk) * 0.25f; \
    const float nv = fmaf(wgt, vv - qq, qq); \
    SS = nv; \
    const float yv = sum16(nv * (Cv)); \
    py[POFF] = yv; \
  }

  #define STEP2(P, I) { \
    STEP1(sX, adnX, P##dx##I, P##ux##I, P##B##I, P##C##I, P##m##I, P##v##I, 0) \
    STEP1(sY, adnY, P##dy##I, P##uy##I, P##B##I, P##C##I, P##m##I, P##v##I, 4) \
    py += DI; }

  DECLH(A) DECLH(B)
  LOADH(A)
  LOADH(B)
  for (int it = 0; it < LL/8; ++it){
    STEP2(A,0) STEP2(A,1) STEP2(A,2) STEP2(A,3)
    LOADH(A)
    STEP2(B,0) STEP2(B,1) STEP2(B,2) STEP2(B,3)
    LOADH(B)
  }
  #undef STEP2
  #undef STEP1
  #undef MV
  #undef LOADH
  #undef DECLH
}

// ---------- K5b: y = (yv + uc*Dp) * silu(res) -> split bf16 hi/lo ----------
__global__ __launch_bounds__(128) void ymerge_split_kernel(const float* __restrict__ y,
                                                           const float* __restrict__ ucb,
                                                           const float* __restrict__ xr,
                                                           const float* __restrict__ Dp,
                                                           ushort_* __restrict__ yh,
                                                           ushort_* __restrict__ yl){
  const int kq = blockIdx.x*128 + threadIdx.x;  // 0..383
  const int m  = blockIdx.y;
  const int k0 = kq*4;
  float4 yv = *(const float4*)(y + (size_t)m*DI + k0);
  float4 u4 = *(const float4*)(ucb + (size_t)m*DI + k0);
  float4 D4 = *(const float4*)(Dp + k0);
  float4 r4 = *(const float4*)(xr + (size_t)m*(2*DI) + DI + k0);
  float4 o;
  o.x = fmaf(u4.x, D4.x, yv.x) * siluf_(r4.x);
  o.y = fmaf(u4.y, D4.y, yv.y) * siluf_(r4.y);
  o.z = fmaf(u4.z, D4.z, yv.z) * siluf_(r4.z);
  o.w = fmaf(u4.w, D4.w, yv.w) * siluf_(r4.w);
  ushort4 hh, ll;
  split2(o.x, hh.x, ll.x); split2(o.y, hh.y, ll.y);
  split2(o.z, hh.z, ll.z); split2(o.w, hh.w, ll.w);
  const size_t i4 = ((size_t)m*DI >> 2) + kq;
  ((ushort4*)yh)[i4] = hh; ((ushort4*)yl)[i4] = ll;
}

// ---------- K6: LN(h)*(1+scale)+shift, SiLU -> split bf16 hi/lo ----------
__global__ __launch_bounds__(256) void lnmod_split_kernel(const float* __restrict__ h,
                                                          const float* __restrict__ g,
                                                          const float* __restrict__ bb,
                                                          const float* __restrict__ eo,
                                                          ushort_* __restrict__ s2h,
                                                          ushort_* __restrict__ s2l){
  const int row = blockIdx.x;
  const int b = row >> 10;
  const float* hp = h + (size_t)row * DM;
  const int tid = threadIdx.x;
  float vals[3];
  float s1 = 0.f, s2 = 0.f;
  #pragma unroll
  for (int i = 0; i < 3; i++){ float v = hp[tid + i*256]; vals[i] = v; s1 += v; s2 += v*v; }
  #pragma unroll
  for (int off = 32; off; off >>= 1){ s1 += __shfl_xor(s1, off); s2 += __shfl_xor(s2, off); }
  __shared__ float wa[4], wb[4];
  if ((tid & 63) == 0){ wa[tid >> 6] = s1; wb[tid >> 6] = s2; }
  __syncthreads();
  s1 = wa[0] + wa[1] + wa[2] + wa[3];
  s2 = wb[0] + wb[1] + wb[2] + wb[3];
  const float m  = s1 * (1.f/768.f);
  const float var = s2 * (1.f/768.f) - m*m;
  const float rs = rsqrtf(var + 1e-5f);
  #pragma unroll
  for (int i = 0; i < 3; i++){
    const int j = tid + i*256;
    float h2 = (vals[i] - m)*rs*g[j] + bb[j];
    const float sc = eo[b*(2*DM) + j];
    const float sh = eo[b*(2*DM) + DM + j];
    h2 = h2*(1.f + sc) + sh;
    float v = siluf_(h2);
    ushort_ hh, ll; split2(v, hh, ll);
    s2h[(size_t)row*DM + j] = hh;
    s2l[(size_t)row*DM + j] = ll;
  }
}

extern "C" void kernel_launch(void* const* d_in, const int* in_sizes, int n_in,
                              void* d_out, int out_size, void* d_ws, size_t ws_size,
                              hipStream_t stream){
  const float* x      = (const float*)d_in[0];
  const float* emb    = (const float*)d_in[1];
  const float* rms_w  = (const float*)d_in[2];
  const float* Win    = (const float*)d_in[3];
  const float* conv_w = (const float*)d_in[4];
  const float* conv_b = (const float*)d_in[5];
  const float* Wx     = (const float*)d_in[6];
  const float* Wdt    = (const float*)d_in[7];
  const float* bdt    = (const float*)d_in[8];
  const float* A_log  = (const float*)d_in[9];
  const float* Dp     = (const float*)d_in[10];
  const float* Wout   = (const float*)d_in[11];
  const float* Wq     = (const float*)d_in[12];
  const float* Wk     = (const float*)d_in[13];
  const float* Wv     = (const float*)d_in[14];
  const float* ln_s_g = (const float*)d_in[15];
  const float* ln_s_b = (const float*)d_in[16];
  const float* ln_c_g = (const float*)d_in[17];
  const float* ln_c_b = (const float*)d_in[18];
  const float* We     = (const float*)d_in[19];
  const float* be     = (const float*)d_in[20];
  const float* ln_h_g = (const float*)d_in[21];
  const float* ln_h_b = (const float*)d_in[22];
  const float* Wo     = (const float*)d_in[23];
  const float* bo     = (const float*)d_in[24];
  float* out = (float*)d_out;

  // ---- workspace layout (f32 offsets) ----
  float* ws  = (float*)d_ws;
  float*  xr  = ws;                         // 2048*3072            = 6291456
  float*  ucb = ws + 6291456;               // 2064*1536            = 3170304
  float*  xdb = ws + 9461760;               // 2064*80              = 165120
  float*  dlt = ws + 9626880;               // 2064*1536            = 3170304
  float*  yb  = ws + 12797184;              // 2048*1536            = 3145728
  float*  hb  = ws + 15942912;              // 2048*768             = 1572864
  float*  eo  = ws + 17515776;              // 2*1536               = 3072
  float2* bst = (float2*)(ws + 17518848);   // 2112 float2          = 4224
  // fresh bf16 region
  ushort_* xnh_h = (ushort_*)(ws + 17523072);
  ushort_* xnh_l = xnh_h + 1572864;
  ushort_* winh  = xnh_l + 1572864;
  ushort_* winl  = winh + 2359296;
  ushort_* yh    = winl + 2359296;
  ushort_* yl    = yh + 3145728;
  // overlays (regions dead by the time these are written)
  ushort_* s2h   = (ushort_*)xdb;                       // after scan
  ushort_* s2l   = s2h + 1572864;
  ushort_* wouth = s2l + 1572864;                       // still in xdb+dlt region
  ushort_* woutl = wouth + 1179648;
  ushort_* woh   = (ushort_*)ucb;                       // after ymerge
  ushort_* wol   = woh + 589824;

  // emb path (independent)
  emb_kernel<<<24, 128, 0, stream>>>(emb, We, be, eo);
  // RMSNorm -> bf16 hi/lo
  rmsnorm_split_kernel<<<2048, 256, 0, stream>>>(x, rms_w, xnh_h, xnh_l);
  // split Win
  split_kernel<<<2304, 256, 0, stream>>>(Win, winh, winl, 589824);
  // xr = xn @ Win^T  (MFMA)
  gemm_mfma<0><<<dim3(24, 16), 256, 0, stream>>>(xnh_h, xnh_l, winh, winl, xr, 2*DI, DM, nullptr, nullptr);
  // uc = silu(conv(u) + cb)
  conv_silu_kernel<<<dim3(6, 2048), 256, 0, stream>>>(xr, conv_w, conv_b, ucb);
  // x_dbl = uc @ Wx^T  (fp32, N=80)
  gemm_nt<0><<<dim3(2, 32), 256, 0, stream>>>(ucb, DI, Wx, DI, xdb, 80, 80, DI, nullptr);
  // Bm row-stats
  bstat_kernel<<<8, 256, 0, stream>>>(xdb, bst);
  // delta = softplus(x_dbl[:, :48] @ Wdt^T + bdt)  (fp32, K=48)
  gemm_nt<1><<<dim3(24, 32), 256, 0, stream>>>(xdb, 80, Wdt, DTR, dlt, DI, DI, DTR, bdt);
  // sequential scan -> raw yv
  scan_kernel<<<dim3(192, 2), 64, 0, stream>>>(dlt, ucb, xdb, bst, A_log, Wq, Wk, Wv,
                                               ln_s_g, ln_s_b, ln_c_g, ln_c_b, yb);
  // split Wout (into dead dlt region)
  split_kernel<<<1152, 256, 0, stream>>>(Wout, wouth, woutl, 294912);
  // y = (yv + uc*Dp)*silu(res) -> bf16 hi/lo
  ymerge_split_kernel<<<dim3(3, 2048), 128, 0, stream>>>(yb, ucb, xr, Dp, yh, yl);
  // h = y @ Wout^T (MFMA)
  gemm_mfma<0><<<dim3(6, 16), 256, 0, stream>>>(yh, yl, wouth, woutl, hb, DM, DI, nullptr, nullptr);
  // split Wo (into dead ucb region)
  split_kernel<<<576, 256, 0, stream>>>(Wo, woh, wol, 147456);
  // h2 = LN(h)*(1+scale)+shift ; s2 = silu(h2) -> bf16 hi/lo
  lnmod_split_kernel<<<2048, 256, 0, stream>>>(hb, ln_h_g, ln_h_b, eo, s2h, s2l);
  // out = x + s2 @ Wo^T + bo (MFMA, EPI2)
  gemm_mfma<2><<<dim3(6, 16), 256, 0, stream>>>(s2h, s2l, woh, wol, out, DM, DM, bo, x);
}

// Round 10
// 650.738 us; speedup vs baseline: 1.3944x; 1.3944x over previous
//
#include <hip/hip_runtime.h>
#include <hip/hip_bf16.h>
#include <cstdint>
#include <cstddef>

#define BB 2
#define LL 1024
#define DM 768
#define DI 1536
#define NS 16
#define DTR 48
#define TEMB_ 1024

typedef unsigned short ushort_;
using bf16x8 = __attribute__((ext_vector_type(8))) short;
using f32x4  = __attribute__((ext_vector_type(4))) float;

static __device__ __forceinline__ float sigmoidf_(float x){ return 1.f/(1.f+__expf(-x)); }
static __device__ __forceinline__ float siluf_(float x){ return x*sigmoidf_(x); }
static __device__ __forceinline__ float softplusf_(float x){ return (x>15.f)? x : log1pf(__expf(x)); }

static __device__ __forceinline__ void split2(float v, ushort_& h, ushort_& l){
  __hip_bfloat16 bh = __float2bfloat16(v);
  float hf = __bfloat162float(bh);
  __hip_bfloat16 bl = __float2bfloat16(v - hf);
  h = *(ushort_*)&bh; l = *(ushort_*)&bl;
}

// ---------- cross-lane helpers: pure-VALU DPP, 16-lane groups ----------
// quad_perm 0xB1 = xor1, 0x4E = xor2; row_half_mirror 0x141 = xor7; row_mirror 0x140 = xor15.
#define DPPX(CTRL, x) __int_as_float(__builtin_amdgcn_update_dpp(0, __float_as_int(x), (CTRL), 0xF, 0xF, true))

static __device__ __forceinline__ float sum16(float x){
  x += DPPX(0xB1, x);
  x += DPPX(0x4E, x);
  x += DPPX(0x141, x);
  x += DPPX(0x140, x);
  return x;
}

// ---------- K0: emb path ----------
__global__ __launch_bounds__(128) void emb_kernel(const float* __restrict__ emb,
                                                  const float* __restrict__ We,
                                                  const float* __restrict__ be,
                                                  float* __restrict__ eo){
  __shared__ float se[TEMB_];
  const int b = blockIdx.x / 12;
  const int jb = (blockIdx.x % 12) * 128;
  for (int i = threadIdx.x; i < TEMB_; i += 128) se[i] = siluf_(emb[b*TEMB_ + i]);
  __syncthreads();
  const int j = jb + threadIdx.x;
  const float* wr = We + (size_t)j * TEMB_;
  float acc = 0.f;
  #pragma unroll 4
  for (int k = 0; k < TEMB_; k += 4){
    acc = fmaf(se[k+0], wr[k+0], acc);
    acc = fmaf(se[k+1], wr[k+1], acc);
    acc = fmaf(se[k+2], wr[k+2], acc);
    acc = fmaf(se[k+3], wr[k+3], acc);
  }
  eo[b*(2*DM) + j] = acc + be[j];
}

// ---------- K1: RMSNorm -> split bf16 hi/lo ----------
__global__ __launch_bounds__(256) void rmsnorm_split_kernel(const float* __restrict__ x,
                                                            const float* __restrict__ w,
                                                            ushort_* __restrict__ xh,
                                                            ushort_* __restrict__ xl){
  const int row = blockIdx.x;
  const int tid = threadIdx.x;
  const float* xp = x + (size_t)row * DM;
  float vals[3];
  float p = 0.f;
  #pragma unroll
  for (int i = 0; i < 3; i++){ float v = xp[tid + i*256]; vals[i] = v; p += v*v; }
  #pragma unroll
  for (int off = 32; off; off >>= 1) p += __shfl_xor(p, off);
  __shared__ float wsum[4];
  if ((tid & 63) == 0) wsum[tid >> 6] = p;
  __syncthreads();
  float total = wsum[0] + wsum[1] + wsum[2] + wsum[3];
  float rs = rsqrtf(total * (1.f/768.f) + 1e-5f);
  #pragma unroll
  for (int i = 0; i < 3; i++){
    int j = tid + i*256;
    float v = vals[i]*rs*w[j];
    ushort_ h, l; split2(v, h, l);
    xh[(size_t)row*DM + j] = h;
    xl[(size_t)row*DM + j] = l;
  }
}

// ---------- generic fp32 -> bf16 hi/lo split ----------
__global__ __launch_bounds__(256) void split_kernel(const float* __restrict__ in,
                                                    ushort_* __restrict__ h,
                                                    ushort_* __restrict__ l, int n4){
  const int i = blockIdx.x*256 + threadIdx.x;
  if (i >= n4) return;
  float4 v = ((const float4*)in)[i];
  ushort4 hh, ll;
  split2(v.x, hh.x, ll.x); split2(v.y, hh.y, ll.y);
  split2(v.z, hh.z, ll.z); split2(v.w, hh.w, ll.w);
  ((ushort4*)h)[i] = hh; ((ushort4*)l)[i] = ll;
}

// ---------- K2: depthwise causal conv (k=4) + bias + SiLU ----------
__global__ __launch_bounds__(256) void conv_silu_kernel(const float* __restrict__ xr,
                                                        const float* __restrict__ cw,
                                                        const float* __restrict__ cb,
                                                        float* __restrict__ uc){
  const int d  = blockIdx.x*256 + threadIdx.x;
  const int bt = blockIdx.y;
  const int t  = bt & (LL-1);
  const float w0 = cw[d*4+0], w1 = cw[d*4+1], w2 = cw[d*4+2], w3 = cw[d*4+3];
  const float* up = xr + (size_t)bt*(2*DI) + d;
  float s = cb[d];
  if (t >= 3) s = fmaf(up[-3*2*DI], w0, s);
  if (t >= 2) s = fmaf(up[-2*2*DI], w1, s);
  if (t >= 1) s = fmaf(up[-1*2*DI], w2, s);
  s = fmaf(up[0], w3, s);
  uc[(size_t)bt*DI + d] = siluf_(s);
}

// ---------- fp32 tiled GEMM (Wx / Wdt):  C = A * B^T ----------
template<int EPI>
__global__ __launch_bounds__(256) void gemm_nt(const float* __restrict__ A, int lda,
                                               const float* __restrict__ B, int ldb,
                                               float* __restrict__ C, int ldc,
                                               int N, int K,
                                               const float* __restrict__ bias){
  __shared__ float As[16][68];
  __shared__ float Bs[16][68];
  const int tid = threadIdx.x;
  const int m0 = blockIdx.y * 64;
  const int n0 = blockIdx.x * 64;
  const int lr = tid >> 2;
  const int lk = (tid & 3) << 2;
  const int tx = tid & 15;
  const int ty = tid >> 4;
  float acc[4][4] = {};
  for (int k0 = 0; k0 < K; k0 += 16){
    float4 ga = *(const float4*)(A + (size_t)(m0 + lr)*lda + k0 + lk);
    float4 gb;
    if (n0 + lr < N) gb = *(const float4*)(B + (size_t)(n0 + lr)*ldb + k0 + lk);
    else             gb = make_float4(0.f,0.f,0.f,0.f);
    __syncthreads();
    As[lk+0][lr] = ga.x; As[lk+1][lr] = ga.y; As[lk+2][lr] = ga.z; As[lk+3][lr] = ga.w;
    Bs[lk+0][lr] = gb.x; Bs[lk+1][lr] = gb.y; Bs[lk+2][lr] = gb.z; Bs[lk+3][lr] = gb.w;
    __syncthreads();
    #pragma unroll
    for (int k = 0; k < 16; k++){
      float4 av = *(const float4*)&As[k][ty*4];
      float4 bv = *(const float4*)&Bs[k][tx*4];
      float a4[4] = {av.x, av.y, av.z, av.w};
      float b4[4] = {bv.x, bv.y, bv.z, bv.w};
      #pragma unroll
      for (int i = 0; i < 4; i++)
        #pragma unroll
        for (int j = 0; j < 4; j++)
          acc[i][j] = fmaf(a4[i], b4[j], acc[i][j]);
    }
  }
  #pragma unroll
  for (int i = 0; i < 4; i++){
    const int row = m0 + ty*4 + i;
    #pragma unroll
    for (int j = 0; j < 4; j++){
      const int col = n0 + tx*4 + j;
      if (col < N){
        float r = acc[i][j];
        if constexpr (EPI == 1) r = softplusf_(r + bias[col]);
        C[(size_t)row*ldc + col] = r;
      }
    }
  }
}

// ---------- split-bf16 MFMA GEMM: C[M,N] = A[M,K] * B[N,K]^T ----------
// BM=128 fixed, BN in {128, 64}. 4 waves. D = Ah*Bh + Ah*Bl + Al*Bh.
template<int EPI, int BN>
__global__ __launch_bounds__(256) void gemm_mfma(const ushort_* __restrict__ Ah, const ushort_* __restrict__ Al,
                                                 const ushort_* __restrict__ Bh, const ushort_* __restrict__ Bl,
                                                 float* __restrict__ C, int ldc, int K,
                                                 const float* __restrict__ bias,
                                                 const float* __restrict__ resid){
  constexpr int LDT = 40;                 // padded row (bf16): 80 B
  constexpr int NT  = BN/32;              // n-frags per wave
  __shared__ ushort_ sA[2][128*LDT];
  __shared__ ushort_ sB[2][BN*LDT];
  const int tid = threadIdx.x;
  const int m0 = blockIdx.y*128, n0 = blockIdx.x*BN;
  const int w = tid>>6, lane = tid&63;
  const int wm = (w>>1)*64, wn = (w&1)*(BN/2);
  const int lr = lane&15, lk = lane>>4;
  // A loader: 128 rows, 2 threads/row, 16 ushorts each
  const int sRowA = tid>>1, sColA = (tid&1)*16;
  const size_t gA = (size_t)(m0+sRowA)*K + sColA;
  // B loader
  const int sRowB = (BN==128) ? (tid>>1) : (tid>>2);
  const int sColB = (BN==128) ? ((tid&1)*16) : ((tid&3)*8);
  const size_t gB = (size_t)(n0+sRowB)*K + sColB;
  f32x4 acc[4][NT] = {};
  for (int k0 = 0; k0 < K; k0 += 32){
    uint4 ah0 = *(const uint4*)(Ah + gA + k0);
    uint4 ah1 = *(const uint4*)(Ah + gA + k0 + 8);
    uint4 al0 = *(const uint4*)(Al + gA + k0);
    uint4 al1 = *(const uint4*)(Al + gA + k0 + 8);
    uint4 bh0, bh1, bl0, bl1;
    if constexpr (BN == 128){
      bh0 = *(const uint4*)(Bh + gB + k0);
      bh1 = *(const uint4*)(Bh + gB + k0 + 8);
      bl0 = *(const uint4*)(Bl + gB + k0);
      bl1 = *(const uint4*)(Bl + gB + k0 + 8);
    } else {
      bh0 = *(const uint4*)(Bh + gB + k0);
      bl0 = *(const uint4*)(Bl + gB + k0);
    }
    __syncthreads();
    *(uint4*)(&sA[0][sRowA*LDT + sColA])     = ah0;
    *(uint4*)(&sA[0][sRowA*LDT + sColA + 8]) = ah1;
    *(uint4*)(&sA[1][sRowA*LDT + sColA])     = al0;
    *(uint4*)(&sA[1][sRowA*LDT + sColA + 8]) = al1;
    if constexpr (BN == 128){
      *(uint4*)(&sB[0][sRowB*LDT + sColB])     = bh0;
      *(uint4*)(&sB[0][sRowB*LDT + sColB + 8]) = bh1;
      *(uint4*)(&sB[1][sRowB*LDT + sColB])     = bl0;
      *(uint4*)(&sB[1][sRowB*LDT + sColB + 8]) = bl1;
    } else {
      *(uint4*)(&sB[0][sRowB*LDT + sColB]) = bh0;
      *(uint4*)(&sB[1][sRowB*LDT + sColB]) = bl0;
    }
    __syncthreads();
    bf16x8 fa[2][4], fb[2][NT];
    #pragma unroll
    for (int mt = 0; mt < 4; mt++){
      fa[0][mt] = *(const bf16x8*)(&sA[0][(wm+mt*16+lr)*LDT + lk*8]);
      fa[1][mt] = *(const bf16x8*)(&sA[1][(wm+mt*16+lr)*LDT + lk*8]);
    }
    #pragma unroll
    for (int nt = 0; nt < NT; nt++){
      fb[0][nt] = *(const bf16x8*)(&sB[0][(wn+nt*16+lr)*LDT + lk*8]);
      fb[1][nt] = *(const bf16x8*)(&sB[1][(wn+nt*16+lr)*LDT + lk*8]);
    }
    #pragma unroll
    for (int mt = 0; mt < 4; mt++)
      #pragma unroll
      for (int nt = 0; nt < NT; nt++){
        acc[mt][nt] = __builtin_amdgcn_mfma_f32_16x16x32_bf16(fa[0][mt], fb[0][nt], acc[mt][nt], 0,0,0);
        acc[mt][nt] = __builtin_amdgcn_mfma_f32_16x16x32_bf16(fa[0][mt], fb[1][nt], acc[mt][nt], 0,0,0);
        acc[mt][nt] = __builtin_amdgcn_mfma_f32_16x16x32_bf16(fa[1][mt], fb[0][nt], acc[mt][nt], 0,0,0);
      }
  }
  #pragma unroll
  for (int mt = 0; mt < 4; mt++){
    #pragma unroll
    for (int nt = 0; nt < NT; nt++){
      const int col = n0 + wn + nt*16 + lr;
      #pragma unroll
      for (int r = 0; r < 4; r++){
        const int row = m0 + wm + mt*16 + lk*4 + r;
        float v = acc[mt][nt][r];
        if constexpr (EPI == 2) v += bias[col] + resid[(size_t)row*ldc + col];
        C[(size_t)row*ldc + col] = v;
      }
    }
  }
}

// ---------- K4: per-(b,t) KV precompute ----------
// mB,vB = row-stats of Bm; e = gc*(Bm-mB); K0 = e@Wk^T; V0 = e@Wv^T.
// record [row][64]: K0[16] | V0[16] | Cm[16] | vB | pad
__global__ __launch_bounds__(256) void kvprep_kernel(const float* __restrict__ x_dbl,
                                                     const float* __restrict__ Wk,
                                                     const float* __restrict__ Wv,
                                                     const float* __restrict__ g_c,
                                                     float* __restrict__ kvrec){
  const int lane = threadIdx.x & 15;
  const int row  = (blockIdx.x*256 + threadIdx.x) >> 4;   // grid 128 -> 2048 rows
  const float Bm = x_dbl[(size_t)row*80 + 48 + lane];
  const float Cm = x_dbl[(size_t)row*80 + 64 + lane];
  const float mB = sum16(Bm) * 0.0625f;
  const float vB = fmaf(sum16(Bm*Bm), 0.0625f, -(mB*mB));
  constexpr int gseq[16] = {0,1,3,2,5,4,6,7,8,9,11,10,13,12,14,15};
  float wkp[16], wvp[16];
  #pragma unroll
  for (int i = 0; i < 16; i++){
    const int c = lane ^ gseq[i];
    wkp[i] = Wk[lane*16 + c];
    wvp[i] = Wv[lane*16 + c];
  }
  float ve = g_c[lane] * (Bm - mB);
  float K0 = ve*wkp[0], V0 = ve*wvp[0];
  #define MVE(i, CTRL) { ve = DPPX(CTRL, ve); K0 = fmaf(ve, wkp[i], K0); V0 = fmaf(ve, wvp[i], V0); }
  MVE(1,0xB1)  MVE(2,0x4E)  MVE(3,0xB1)  MVE(4,0x141)
  MVE(5,0xB1)  MVE(6,0x4E)  MVE(7,0xB1)  MVE(8,0x140)
  MVE(9,0xB1)  MVE(10,0x4E) MVE(11,0xB1) MVE(12,0x141)
  MVE(13,0xB1) MVE(14,0x4E) MVE(15,0xB1)
  #undef MVE
  float* r = kvrec + (size_t)row*64;
  r[lane]      = K0;
  r[16 + lane] = V0;
  r[32 + lane] = Cm;
  if (lane == 0) r[48] = vB;
}

// ---------- K5: sequential scan (768 waves, 4 chains/wave) ----------
// Serial per step: LN(state) + q-matvec only; k,v collapse to fma(rc,K0,kb).
__global__ __launch_bounds__(64,1) void scan_kernel(const float* __restrict__ delta,
                                                    const float* __restrict__ uc,
                                                    const float* __restrict__ kvrec,
                                                    const float* __restrict__ A_log,
                                                    const float* __restrict__ Wq,
                                                    const float* __restrict__ Wk,
                                                    const float* __restrict__ Wv,
                                                    const float* __restrict__ g_s, const float* __restrict__ b_s,
                                                    const float* __restrict__ b_c,
                                                    float* __restrict__ y){
  const int lane  = threadIdx.x & 15;
  const int chain = threadIdx.x >> 4;       // 0..3
  const int d = blockIdx.x * 4 + chain;     // grid.x = 384
  const int b = blockIdx.y;

  constexpr int gseq[16] = {0,1,3,2,5,4,6,7,8,9,11,10,13,12,14,15};
  float wq[16];
  #pragma unroll
  for (int i = 0; i < 16; i++) wq[i] = Wq[lane*16 + (lane ^ gseq[i])];
  // kb = Wk@bc, vb = Wv@bc (per output lane)
  float kb = 0.f, vb = 0.f;
  #pragma unroll
  for (int c = 0; c < 16; c++){
    const float bc = b_c[c];
    kb = fmaf(Wk[lane*16 + c], bc, kb);
    vb = fmaf(Wv[lane*16 + c], bc, vb);
  }
  const float adn = -__expf(A_log[d*16 + lane]);
  const float gs = g_s[lane], bs0 = b_s[lane];

  const float* pd = delta + (size_t)b*LL*DI + d;
  const float* pu = uc    + (size_t)b*LL*DI + d;
  const float* pk = kvrec + (size_t)b*LL*64;
  float* py = y + (size_t)b*LL*DI + d;

  float s = 0.f;
  float dA0,dA1,dA2,dA3, kk0,kk1,kk2,kk3, vv0,vv1,vv2,vv3, cc0,cc1,cc2,cc3;

  #define DECLRAW(P) float P##d0,P##d1,P##d2,P##d3, P##u0,P##u1,P##u2,P##u3, \
                           P##K0,P##K1,P##K2,P##K3, P##V0,P##V1,P##V2,P##V3, \
                           P##C0,P##C1,P##C2,P##C3, P##b0,P##b1,P##b2,P##b3;
  #define LOADRAW(P) { \
    P##d0=pd[0]; P##d1=pd[DI]; P##d2=pd[2*DI]; P##d3=pd[3*DI]; \
    P##u0=pu[0]; P##u1=pu[DI]; P##u2=pu[2*DI]; P##u3=pu[3*DI]; \
    P##K0=pk[lane];     P##K1=pk[64+lane];  P##K2=pk[128+lane]; P##K3=pk[192+lane]; \
    P##V0=pk[16+lane];  P##V1=pk[80+lane];  P##V2=pk[144+lane]; P##V3=pk[208+lane]; \
    P##C0=pk[32+lane];  P##C1=pk[96+lane];  P##C2=pk[160+lane]; P##C3=pk[224+lane]; \
    P##b0=pk[48]; P##b1=pk[112]; P##b2=pk[176]; P##b3=pk[240]; \
    pd += 4*DI; pu += 4*DI; pk += 256; }
  #define PREP1(P, I) { \
    dA##I = __expf(P##d##I * adn); \
    const float al_ = P##d##I * P##u##I; \
    const float rc_ = al_ * rsqrtf(fmaf(al_*al_, P##b##I, 1e-5f)); \
    kk##I = fmaf(rc_, P##K##I, kb); \
    vv##I = fmaf(rc_, P##V##I, vb); \
    cc##I = P##C##I; }
  #define PREPALL(P) PREP1(P,0) PREP1(P,1) PREP1(P,2) PREP1(P,3)
  #define MV(i, CTRL) { vs = DPPX(CTRL, vs); qq = fmaf(vs, wq[i], qq); }
  #define STEP(I) { \
    const float st = dA##I * s; \
    const float ssum = sum16(st); \
    const float ssq  = sum16(st*st); \
    const float m_ = ssum * 0.0625f; \
    const float v_ = fmaf(ssq, 0.0625f, -(m_*m_)); \
    const float k1 = rsqrtf(v_ + 1e-5f) * gs; \
    float vs = fmaf(st, k1, fmaf(-m_, k1, bs0)); \
    float qq = vs*wq[0]; \
    MV(1,0xB1)  MV(2,0x4E)  MV(3,0xB1)  MV(4,0x141) \
    MV(5,0xB1)  MV(6,0x4E)  MV(7,0xB1)  MV(8,0x140) \
    MV(9,0xB1)  MV(10,0x4E) MV(11,0xB1) MV(12,0x141) \
    MV(13,0xB1) MV(14,0x4E) MV(15,0xB1) \
    const float wgt = sum16(qq*kk##I) * 0.25f; \
    const float nv = fmaf(wgt, vv##I - qq, qq); \
    s = nv; \
    const float yv = sum16(nv * cc##I); \
    py[0] = yv; py += DI; }

  DECLRAW(A) DECLRAW(B)
  LOADRAW(A)
  LOADRAW(B)
  for (int it = 0; it < LL/8; ++it){
    PREPALL(A)
    LOADRAW(A)
    STEP(0) STEP(1) STEP(2) STEP(3)
    PREPALL(B)
    LOADRAW(B)
    STEP(0) STEP(1) STEP(2) STEP(3)
  }
  #undef STEP
  #undef MV
  #undef PREPALL
  #undef PREP1
  #undef LOADRAW
  #undef DECLRAW
}

// ---------- K5b: y = (yv + uc*Dp) * silu(res) -> split bf16 hi/lo ----------
__global__ __launch_bounds__(128) void ymerge_split_kernel(const float* __restrict__ y,
                                                           const float* __restrict__ ucb,
                                                           const float* __restrict__ xr,
                                                           const float* __restrict__ Dp,
                                                           ushort_* __restrict__ yh,
                                                           ushort_* __restrict__ yl){
  const int kq = blockIdx.x*128 + threadIdx.x;
  const int m  = blockIdx.y;
  const int k0 = kq*4;
  float4 yv = *(const float4*)(y + (size_t)m*DI + k0);
  float4 u4 = *(const float4*)(ucb + (size_t)m*DI + k0);
  float4 D4 = *(const float4*)(Dp + k0);
  float4 r4 = *(const float4*)(xr + (size_t)m*(2*DI) + DI + k0);
  float4 o;
  o.x = fmaf(u4.x, D4.x, yv.x) * siluf_(r4.x);
  o.y = fmaf(u4.y, D4.y, yv.y) * siluf_(r4.y);
  o.z = fmaf(u4.z, D4.z, yv.z) * siluf_(r4.z);
  o.w = fmaf(u4.w, D4.w, yv.w) * siluf_(r4.w);
  ushort4 hh, ll;
  split2(o.x, hh.x, ll.x); split2(o.y, hh.y, ll.y);
  split2(o.z, hh.z, ll.z); split2(o.w, hh.w, ll.w);
  const size_t i4 = ((size_t)m*DI >> 2) + kq;
  ((ushort4*)yh)[i4] = hh; ((ushort4*)yl)[i4] = ll;
}

// ---------- K6: LN(h)*(1+scale)+shift, SiLU -> split bf16 hi/lo ----------
__global__ __launch_bounds__(256) void lnmod_split_kernel(const float* __restrict__ h,
                                                          const float* __restrict__ g,
                                                          const float* __restrict__ bb,
                                                          const float* __restrict__ eo,
                                                          ushort_* __restrict__ s2h,
                                                          ushort_* __restrict__ s2l){
  const int row = blockIdx.x;
  const int b = row >> 10;
  const float* hp = h + (size_t)row * DM;
  const int tid = threadIdx.x;
  float vals[3];
  float s1 = 0.f, s2 = 0.f;
  #pragma unroll
  for (int i = 0; i < 3; i++){ float v = hp[tid + i*256]; vals[i] = v; s1 += v; s2 += v*v; }
  #pragma unroll
  for (int off = 32; off; off >>= 1){ s1 += __shfl_xor(s1, off); s2 += __shfl_xor(s2, off); }
  __shared__ float wa[4], wb[4];
  if ((tid & 63) == 0){ wa[tid >> 6] = s1; wb[tid >> 6] = s2; }
  __syncthreads();
  s1 = wa[0] + wa[1] + wa[2] + wa[3];
  s2 = wb[0] + wb[1] + wb[2] + wb[3];
  const float m  = s1 * (1.f/768.f);
  const float var = s2 * (1.f/768.f) - m*m;
  const float rs = rsqrtf(var + 1e-5f);
  #pragma unroll
  for (int i = 0; i < 3; i++){
    const int j = tid + i*256;
    float h2 = (vals[i] - m)*rs*g[j] + bb[j];
    const float sc = eo[b*(2*DM) + j];
    const float sh = eo[b*(2*DM) + DM + j];
    h2 = h2*(1.f + sc) + sh;
    float v = siluf_(h2);
    ushort_ hh, ll; split2(v, hh, ll);
    s2h[(size_t)row*DM + j] = hh;
    s2l[(size_t)row*DM + j] = ll;
  }
}

extern "C" void kernel_launch(void* const* d_in, const int* in_sizes, int n_in,
                              void* d_out, int out_size, void* d_ws, size_t ws_size,
                              hipStream_t stream){
  const float* x      = (const float*)d_in[0];
  const float* emb    = (const float*)d_in[1];
  const float* rms_w  = (const float*)d_in[2];
  const float* Win    = (const float*)d_in[3];
  const float* conv_w = (const float*)d_in[4];
  const float* conv_b = (const float*)d_in[5];
  const float* Wx     = (const float*)d_in[6];
  const float* Wdt    = (const float*)d_in[7];
  const float* bdt    = (const float*)d_in[8];
  const float* A_log  = (const float*)d_in[9];
  const float* Dp     = (const float*)d_in[10];
  const float* Wout   = (const float*)d_in[11];
  const float* Wq     = (const float*)d_in[12];
  const float* Wk     = (const float*)d_in[13];
  const float* Wv     = (const float*)d_in[14];
  const float* ln_s_g = (const float*)d_in[15];
  const float* ln_s_b = (const float*)d_in[16];
  const float* ln_c_g = (const float*)d_in[17];
  const float* ln_c_b = (const float*)d_in[18];
  const float* We     = (const float*)d_in[19];
  const float* be     = (const float*)d_in[20];
  const float* ln_h_g = (const float*)d_in[21];
  const float* ln_h_b = (const float*)d_in[22];
  const float* Wo     = (const float*)d_in[23];
  const float* bo     = (const float*)d_in[24];
  float* out = (float*)d_out;

  // ---- workspace layout (f32 offsets) ----
  float* ws  = (float*)d_ws;
  float*  xr  = ws;                         // 2048*3072            = 6291456
  float*  ucb = ws + 6291456;               // 2064*1536            = 3170304
  float*  xdb = ws + 9461760;               // 2064*80              = 165120
  float*  dlt = ws + 9626880;               // 2064*1536            = 3170304
  float*  yb  = ws + 12797184;              // 2048*1536            = 3145728
  float*  hb  = ws + 15942912;              // 2048*768             = 1572864
  float*  eo  = ws + 17515776;              // 2*1536               = 3072
  float*  kvr = ws + 17518848;              // 2064*64              = 132096
  // fresh bf16 region
  ushort_* xnh_h = (ushort_*)(ws + 17650944);
  ushort_* xnh_l = xnh_h + 1572864;
  ushort_* winh  = xnh_l + 1572864;
  ushort_* winl  = winh + 2359296;
  ushort_* yh    = winl + 2359296;
  ushort_* yl    = yh + 3145728;
  // overlays in dead fp32 regions
  ushort_* s2h   = (ushort_*)xdb;            // xdb+dlt region, after scan
  ushort_* s2l   = s2h + 1572864;
  ushort_* wouth = s2l + 1572864;
  ushort_* woutl = wouth + 1179648;
  ushort_* woh   = (ushort_*)ucb;            // ucb region, after ymerge
  ushort_* wol   = woh + 589824;

  // emb path (independent)
  emb_kernel<<<24, 128, 0, stream>>>(emb, We, be, eo);
  // RMSNorm -> bf16 hi/lo
  rmsnorm_split_kernel<<<2048, 256, 0, stream>>>(x, rms_w, xnh_h, xnh_l);
  // split Win
  split_kernel<<<2304, 256, 0, stream>>>(Win, winh, winl, 589824);
  // xr = xn @ Win^T  (MFMA, 128x128)
  gemm_mfma<0,128><<<dim3(24, 16), 256, 0, stream>>>(xnh_h, xnh_l, winh, winl, xr, 2*DI, DM, nullptr, nullptr);
  // uc = silu(conv(u) + cb)
  conv_silu_kernel<<<dim3(6, 2048), 256, 0, stream>>>(xr, conv_w, conv_b, ucb);
  // x_dbl = uc @ Wx^T  (fp32, N=80)
  gemm_nt<0><<<dim3(2, 32), 256, 0, stream>>>(ucb, DI, Wx, DI, xdb, 80, 80, DI, nullptr);
  // KV precompute
  kvprep_kernel<<<128, 256, 0, stream>>>(xdb, Wk, Wv, ln_c_g, kvr);
  // delta = softplus(x_dbl[:, :48] @ Wdt^T + bdt)  (fp32, K=48)
  gemm_nt<1><<<dim3(24, 32), 256, 0, stream>>>(xdb, 80, Wdt, DTR, dlt, DI, DI, DTR, bdt);
  // sequential scan -> raw yv
  scan_kernel<<<dim3(384, 2), 64, 0, stream>>>(dlt, ucb, kvr, A_log, Wq, Wk, Wv,
                                               ln_s_g, ln_s_b, ln_c_b, yb);
  // split Wout (into dead dlt region)
  split_kernel<<<1152, 256, 0, stream>>>(Wout, wouth, woutl, 294912);
  // y = (yv + uc*Dp)*silu(res) -> bf16 hi/lo
  ymerge_split_kernel<<<dim3(3, 2048), 128, 0, stream>>>(yb, ucb, xr, Dp, yh, yl);
  // h = y @ Wout^T (MFMA, 128x64 tiles -> 192 blocks)
  gemm_mfma<0,64><<<dim3(12, 16), 256, 0, stream>>>(yh, yl, wouth, woutl, hb, DM, DI, nullptr, nullptr);
  // split Wo (into dead ucb region)
  split_kernel<<<576, 256, 0, stream>>>(Wo, woh, wol, 147456);
  // h2 = LN(h)*(1+scale)+shift ; s2 = silu(h2) -> bf16 hi/lo
  lnmod_split_kernel<<<2048, 256, 0, stream>>>(hb, ln_h_g, ln_h_b, eo, s2h, s2l);
  // out = x + s2 @ Wo^T + bo (MFMA, EPI2)
  gemm_mfma<2,64><<<dim3(12, 16), 256, 0, stream>>>(s2h, s2l, woh, wol, out, DM, DM, bo, x);
}